// Round 14
// baseline (463.427 us; speedup 1.0000x reference)
//
#include <hip/hip_runtime.h>
#include <hip/hip_cooperative_groups.h>
#include <math.h>

namespace cg = cooperative_groups;

#define BN_EPS 0.001f
#define CHUNK 1024          // edges per chunk; nchunk = ceil(ne/CHUNK) must be <= 2048
#define MAXBUCK 1024        // nbuck = ceil(n/64) must be <= 1024

typedef __attribute__((ext_vector_type(8))) short bf16x8;
typedef __attribute__((ext_vector_type(4))) float f32x4;
typedef __attribute__((ext_vector_type(2))) float f32x2;

__device__ inline unsigned bf16rne(float f) {
  unsigned u = __float_as_uint(f);
  return (u + 0x7fffu + ((u >> 16) & 1u)) >> 16;
}
__device__ inline float bflo(unsigned r) { return __uint_as_float(r << 16); }
__device__ inline float bfhi(unsigned r) { return __uint_as_float(r & 0xffff0000u); }

// ---------------- fused CSR build: one cooperative kernel, 5 phases ----------------
// grid = max(nchunk, nbuck) blocks x 256. Phases:
// 1: per-chunk LDS histogram -> ghist[c][bk]
// 2: per-bucket exclusive scan over chunks (in place) + btot
// 3: block 0: exclusive scan of btot -> bbase
// 4: per-chunk scatter of packed records to exact slots (LDS cursors)
// 5: per-bucket: hist -> node scan -> deg/isd/offsets -> CSR fill
__global__ __launch_bounds__(256) void k_csr(const int2* __restrict__ ep, int ne,
                                             int nchunk, int nbuck, int n,
                                             int* __restrict__ ghist,
                                             int* __restrict__ btot,
                                             int* __restrict__ bbase,
                                             unsigned* __restrict__ bins,
                                             int* __restrict__ deg,
                                             float* __restrict__ isd,
                                             int* __restrict__ offsets,
                                             int* __restrict__ csr_dst) {
  cg::grid_group grid = cg::this_grid();
  __shared__ int sh[MAXBUCK];
  int blk = blockIdx.x, t = threadIdx.x;

  // ---- phase 1: ehist for chunk blk ----
  if (blk < nchunk) {
    for (int i = t; i < nbuck; i += 256) sh[i] = 0;
    __syncthreads();
    int base = blk * CHUNK, end = min(base + CHUNK, ne);
    for (int e = base + t; e < end; e += 256) atomicAdd(&sh[ep[e].x >> 6], 1);
    __syncthreads();
    int* row = ghist + (size_t)blk * nbuck;
    for (int i = t; i < nbuck; i += 256) row[i] = sh[i];
  }
  grid.sync();

  // ---- phase 2: per-bucket (b = blk) exclusive scan over chunks ----
  if (blk < nbuck) {
    int G = (nchunk + 255) >> 8;  // <= 8
    int vals[8];
    int c0 = t * G, ts = 0;
#pragma unroll
    for (int g = 0; g < 8; ++g) {
      int v = 0;
      if (g < G) {
        int c = c0 + g;
        if (c < nchunk) v = ghist[(size_t)c * nbuck + blk];
      }
      vals[g] = v;
      ts += v;
    }
    sh[t] = ts;
    __syncthreads();
    int* src = sh;
    int* dst = sh + 256;
    for (int off = 1; off < 256; off <<= 1) {
      int x = src[t];
      if (t >= off) x += src[t - off];
      dst[t] = x;
      __syncthreads();
      int* tmp = src; src = dst; dst = tmp;
    }
    int run = src[t] - ts;  // exclusive base for this thread
    int total = src[255];
    for (int g = 0; g < G; ++g) {
      int c = c0 + g;
      if (c < nchunk) ghist[(size_t)c * nbuck + blk] = run;
      run += vals[g];
    }
    if (t == 0) btot[blk] = total;
  }
  grid.sync();

  // ---- phase 3: block 0 scans bucket totals -> bbase ----
  if (blk == 0) {
    int G = (nbuck + 255) >> 8;  // <= 4
    int vals[4];
    int c0 = t * G, ts = 0;
#pragma unroll
    for (int g = 0; g < 4; ++g) {
      int v = 0;
      if (g < G) {
        int c = c0 + g;
        if (c < nbuck) v = btot[c];
      }
      vals[g] = v;
      ts += v;
    }
    sh[t] = ts;
    __syncthreads();
    int* src = sh;
    int* dst = sh + 256;
    for (int off = 1; off < 256; off <<= 1) {
      int x = src[t];
      if (t >= off) x += src[t - off];
      dst[t] = x;
      __syncthreads();
      int* tmp = src; src = dst; dst = tmp;
    }
    int run = src[t] - ts;
    for (int g = 0; g < G; ++g) {
      int c = c0 + g;
      if (c < nbuck) bbase[c] = run;
      run += vals[g];
    }
  }
  grid.sync();

  // ---- phase 4: ebin for chunk blk (record: dst | (src&63)<<17) ----
  if (blk < nchunk) {
    const int* row = ghist + (size_t)blk * nbuck;
    for (int i = t; i < nbuck; i += 256) sh[i] = bbase[i] + row[i];
    __syncthreads();
    int base = blk * CHUNK, end = min(base + CHUNK, ne);
    for (int e = base + t; e < end; e += 256) {
      int2 p = ep[e];
      int pos = atomicAdd(&sh[p.x >> 6], 1);
      bins[pos] = (unsigned)p.y | ((unsigned)(p.x & 63) << 17);
    }
  }
  grid.sync();

  // ---- phase 5: bfinal for bucket blk ----
  if (blk < nbuck) {
    int* h64 = sh;
    int* cur64 = sh + 64;
    if (t < 64) h64[t] = 0;
    __syncthreads();
    int s = bbase[blk], cnt = btot[blk];
    for (int i = t; i < cnt; i += 256) atomicAdd(&h64[bins[s + i] >> 17], 1);
    __syncthreads();
    if (t == 0) {
      int run = s;
      for (int j = 0; j < 64; ++j) { cur64[j] = run; run += h64[j]; }
    }
    __syncthreads();
    if (t < 64) {
      int node = (blk << 6) + t;
      if (node < n) {
        deg[node] = h64[t];
        offsets[node] = cur64[t];
        isd[node] = 1.0f / sqrtf((float)h64[t]);  // deg==0 -> +inf, matches jnp.power
      }
    }
    __syncthreads();
    for (int i = t; i < cnt; i += 256) {
      unsigned r = bins[s + i];
      int pos = atomicAdd(&cur64[r >> 17], 1);
      csr_dst[pos] = (int)(r & 0x1FFFFu);
    }
  }
}

// ---------------- split-bf16 MFMA GEMM, B staged in LDS ----------------
// One 1024-thread block per 256 rows. Outputs: Tb8 = fp8(isd*t), Th = bf16(0.5*deg*t).
__global__ __launch_bounds__(1024, 4) void k_gemm(const float* __restrict__ X,
                                                  const float* __restrict__ W,
                                                  const float* __restrict__ b,
                                                  const float* __restrict__ isd,
                                                  const int* __restrict__ deg,
                                                  unsigned* __restrict__ Th,
                                                  unsigned char* __restrict__ Tb8, int M) {
  __shared__ unsigned short WhL[16384];  // fragment-major: frag*512 + lane*8 + j
  __shared__ unsigned short WlL[16384];
  int tid = threadIdx.x;

#pragma unroll
  for (int it = 0; it < 4; ++it) {
    int q = tid + it * 1024;
    int k = q >> 5;
    int c0 = (q & 31) * 4;
    float4 v = ((const float4*)W)[q];
    float vv[4] = {v.x, v.y, v.z, v.w};
#pragma unroll
    for (int j2 = 0; j2 < 4; ++j2) {
      int col = c0 + j2;
      float x = vv[j2];
      unsigned short hh = (unsigned short)(__float_as_uint(x) >> 16);
      float rem = x - __uint_as_float((unsigned)hh << 16);
      int frag = ((col >> 4) << 2) | (k >> 5);
      int ln = (((k >> 3) & 3) << 4) | (col & 15);
      int addr = frag * 512 + ln * 8 + (k & 7);
      WhL[addr] = hh;
      WlL[addr] = (unsigned short)bf16rne(rem);
    }
  }

  int wave = tid >> 6, lane = tid & 63;
  int r16 = lane & 15, kq = lane >> 4;
  int rowbase = blockIdx.x * 256 + wave * 16;
  int arow = rowbase + r16;
  bool aok = arow < M;
  const float* xr = X + ((size_t)arow << 7);

  bf16x8 ah[4], al[4];
#pragma unroll
  for (int ks = 0; ks < 4; ++ks) {
    int k0 = ks * 32 + kq * 8;
    float4 v0 = aok ? *(const float4*)(xr + k0) : make_float4(0.f, 0.f, 0.f, 0.f);
    float4 v1 = aok ? *(const float4*)(xr + k0 + 4) : make_float4(0.f, 0.f, 0.f, 0.f);
    float f[8] = {v0.x, v0.y, v0.z, v0.w, v1.x, v1.y, v1.z, v1.w};
    bf16x8 h8, l8;
#pragma unroll
    for (int j = 0; j < 8; ++j) {
      unsigned short hh = (unsigned short)(__float_as_uint(f[j]) >> 16);
      float rem = f[j] - __uint_as_float((unsigned)hh << 16);
      h8[j] = (short)hh;
      l8[j] = (short)bf16rne(rem);
    }
    ah[ks] = h8;
    al[ks] = l8;
  }
  __syncthreads();

  f32x4 acc[8] = {};
#pragma unroll
  for (int ct = 0; ct < 8; ++ct) {
#pragma unroll
    for (int ks = 0; ks < 4; ++ks) {
      int base = (ct * 4 + ks) * 512 + lane * 8;
      bf16x8 bh = *(const bf16x8*)&WhL[base];
      bf16x8 bl = *(const bf16x8*)&WlL[base];
      acc[ct] = __builtin_amdgcn_mfma_f32_16x16x32_bf16(ah[ks], bh, acc[ct], 0, 0, 0);
      acc[ct] = __builtin_amdgcn_mfma_f32_16x16x32_bf16(ah[ks], bl, acc[ct], 0, 0, 0);
      acc[ct] = __builtin_amdgcn_mfma_f32_16x16x32_bf16(al[ks], bh, acc[ct], 0, 0, 0);
    }
  }

  int orow[4];
  float isdr[4], degr[4];
#pragma unroll
  for (int r = 0; r < 4; ++r) {
    orow[r] = rowbase + kq * 4 + r;
    bool ok = orow[r] < M;
    isdr[r] = ok ? isd[orow[r]] : 0.f;
    degr[r] = ok ? 0.5f * (float)deg[orow[r]] : 0.f;
  }
#pragma unroll
  for (int ct = 0; ct < 8; ++ct) {
    int col = ct * 16 + r16;
    float bias = b[col];
#pragma unroll
    for (int r = 0; r < 4; ++r) {
      float v = acc[ct][r] + bias;
      bool ok = orow[r] < M;
      float sv = v * isdr[r];
      float so = __shfl_xor(sv, 1);
      int pk01 = __builtin_amdgcn_cvt_pk_fp8_f32(sv, so, 0, false);
      int pk23 = __shfl_xor(pk01, 2);
      if (ok && (r16 & 3) == 0) {
        unsigned dword = ((unsigned)pk01 & 0xFFFFu) | ((unsigned)pk23 << 16);
        *(unsigned*)&Tb8[((size_t)orow[r] << 7) + ct * 16 + r16] = dword;
      }
      float tv = degr[r] * v;
      float to = __shfl_xor(tv, 1);
      if (ok && !(r16 & 1)) {
        unsigned pk = bf16rne(tv) | (bf16rne(to) << 16);
        Th[((size_t)orow[r] << 6) + ct * 8 + (r16 >> 1)] = pk;
      }
    }
  }
}

// ---------------- gather: HALF-WAVE per node (2 nodes/wave), fp8 dword loads ----------
__global__ __launch_bounds__(256) void k_gather(
    const unsigned* __restrict__ Th, const unsigned char* __restrict__ Tb8,
    const int* __restrict__ deg, const float* __restrict__ isd,
    const int* __restrict__ offsets, const int* __restrict__ csr_dst,
    const float* __restrict__ mm, const float* __restrict__ var,
    const float* __restrict__ gamma, const float* __restrict__ beta,
    float* __restrict__ out, int n) {
  int wave = threadIdx.x >> 6;
  int lane = threadIdx.x & 63;
  int half = lane >> 5;
  int l32 = lane & 31;
  int pair = blockIdx.x * 4 + wave;
  int i = 2 * pair + half;
  if (2 * pair >= n) return;
  bool iok = i < n;
  int degi = iok ? deg[i] : 0;
  int start = iok ? offsets[i] : 0;
  int dother = __shfl(degi, lane ^ 32);
  int dmax = max(degi, dother);
  const unsigned* myrows = (const unsigned*)Tb8 + l32;

  f32x2 accA[8] = {}, accB[8] = {};
  int sl = l32 & 7;
  for (int e = 0; e < dmax; e += 8) {
    int dv = (e + sl < degi) ? csr_dst[start + e + sl] : i;
    unsigned r8[8];
#pragma unroll
    for (int j = 0; j < 8; ++j) {
      int idx = __shfl(dv, (half << 5) + j);
      r8[j] = myrows[(unsigned)idx << 5];
    }
#pragma unroll
    for (int j = 0; j < 8; ++j) {
      int rr = (e + j < degi) ? (int)r8[j] : 0;
      accA[j] += __builtin_amdgcn_cvt_pk_f32_fp8(rr, false);
      accB[j] += __builtin_amdgcn_cvt_pk_f32_fp8(rr, true);
    }
  }
  f32x2 sA = ((accA[0] + accA[1]) + (accA[2] + accA[3])) +
             ((accA[4] + accA[5]) + (accA[6] + accA[7]));
  f32x2 sB = ((accB[0] + accB[1]) + (accB[2] + accB[3])) +
             ((accB[4] + accB[5]) + (accB[6] + accB[7]));

  if (!iok) return;
  float4 aggv = make_float4(0.f, 0.f, 0.f, 0.f);
  if (degi > 0) {
    uint2 th = ((const uint2*)(Th + ((size_t)i << 6)))[l32];
    float hsi = 0.5f * isd[i];
    aggv.x = hsi * sA.x + bflo(th.x);
    aggv.y = hsi * sA.y + bfhi(th.x);
    aggv.z = hsi * sB.x + bflo(th.y);
    aggv.w = hsi * sB.y + bfhi(th.y);
  }
  float4 mmv = ((const float4*)mm)[l32];
  float4 vv = ((const float4*)var)[l32];
  float4 gv = ((const float4*)gamma)[l32];
  float4 bv = ((const float4*)beta)[l32];
  float4 res;
  res.x = (aggv.x - mmv.x) * rsqrtf(vv.x + BN_EPS) * gv.x + bv.x;
  res.y = (aggv.y - mmv.y) * rsqrtf(vv.y + BN_EPS) * gv.y + bv.y;
  res.z = (aggv.z - mmv.z) * rsqrtf(vv.z + BN_EPS) * gv.z + bv.z;
  res.w = (aggv.w - mmv.w) * rsqrtf(vv.w + BN_EPS) * gv.w + bv.w;
  ((float4*)(out + ((size_t)i << 7)))[l32] = res;
}

static inline size_t align_up(size_t x) { return (x + 255) & ~(size_t)255; }

extern "C" void kernel_launch(void* const* d_in, const int* in_sizes, int n_in,
                              void* d_out, int out_size, void* d_ws, size_t ws_size,
                              hipStream_t stream) {
  const int2* ep = (const int2*)d_in[0];
  const float* X = (const float*)d_in[1];
  const float* W = (const float*)d_in[2];
  const float* b = (const float*)d_in[3];
  const float* gamma = (const float*)d_in[4];
  const float* beta = (const float*)d_in[5];
  const float* mm = (const float*)d_in[6];
  const float* var = (const float*)d_in[7];
  float* out = (float*)d_out;

  int ne = in_sizes[0] / 2;
  int n = in_sizes[1] / 128;
  int nbuck = (n + 63) >> 6;              // <= MAXBUCK
  int nchunk = (ne + CHUNK - 1) / CHUNK;  // <= 2048

  char* p = (char*)d_ws;
  int* deg = (int*)p;        p += align_up((size_t)n * 4);
  float* isd = (float*)p;    p += align_up((size_t)n * 4);
  int* offsets = (int*)p;    p += align_up((size_t)n * 4);
  int* btot = (int*)p;       p += align_up((size_t)nbuck * 4);
  int* bbase = (int*)p;      p += align_up((size_t)nbuck * 4);
  int* ghist = (int*)p;      p += align_up((size_t)nchunk * nbuck * 4);
  int* csr_dst = (int*)p;    p += align_up((size_t)ne * 4);
  unsigned* bins = (unsigned*)p; p += align_up((size_t)ne * 4);
  unsigned* Th = (unsigned*)p;   p += align_up((size_t)n * 64 * 4);
  unsigned char* Tb8 = (unsigned char*)p; p += align_up((size_t)n * 128);

  int gdim = nchunk > nbuck ? nchunk : nbuck;
  void* args[] = {(void*)&ep, (void*)&ne, (void*)&nchunk, (void*)&nbuck, (void*)&n,
                  (void*)&ghist, (void*)&btot, (void*)&bbase, (void*)&bins,
                  (void*)&deg, (void*)&isd, (void*)&offsets, (void*)&csr_dst};
  hipLaunchCooperativeKernel((void*)k_csr, dim3(gdim), dim3(256), args, 0, stream);

  k_gemm<<<(n + 255) / 256, 1024, 0, stream>>>(X, W, b, isd, deg, Th, Tb8, n);
  int pairs = (n + 1) / 2;
  k_gather<<<(pairs + 3) / 4, 256, 0, stream>>>(Th, Tb8, deg, isd, offsets, csr_dst,
                                                mm, var, gamma, beta, out, n);
}

// Round 15
// 86.511 us; speedup vs baseline: 5.3569x; 5.3569x over previous
//
#include <hip/hip_runtime.h>
#include <math.h>

#define BN_EPS 0.001f
#define CHUNK 2048          // edges per chunk; nchunk = ceil(ne/CHUNK) must be <= 512
#define MAXBUCK 1024        // nbuck = ceil(n/64) must be <= 1024

typedef __attribute__((ext_vector_type(8))) short bf16x8;
typedef __attribute__((ext_vector_type(4))) float f32x4;
typedef __attribute__((ext_vector_type(2))) float f32x2;

__device__ inline unsigned bf16rne(float f) {
  unsigned u = __float_as_uint(f);
  return (u + 0x7fffu + ((u >> 16) & 1u)) >> 16;
}
__device__ inline float bflo(unsigned r) { return __uint_as_float(r << 16); }
__device__ inline float bfhi(unsigned r) { return __uint_as_float(r & 0xffff0000u); }

// ---------------- pass 1: per-chunk LDS histogram by bucket (src>>6) ----------------
__global__ __launch_bounds__(256) void k_ehist(const int2* __restrict__ ep, int ne,
                                               int nbuck, int* __restrict__ ghist) {
  __shared__ int h[MAXBUCK];
  int c = blockIdx.x, t = threadIdx.x;
  for (int i = t; i < nbuck; i += 256) h[i] = 0;
  __syncthreads();
  int base = c * CHUNK;
  int end = min(base + CHUNK, ne);
  for (int e = base + t; e < end; e += 256) atomicAdd(&h[ep[e].x >> 6], 1);
  __syncthreads();
  int* row = ghist + (size_t)c * nbuck;
  for (int i = t; i < nbuck; i += 256) row[i] = h[i];
}

// ---------------- pass 2a: per-bucket exclusive scan over chunks (in place) + totals ----
__global__ __launch_bounds__(512) void k_bscan(int* __restrict__ ghist, int nchunk,
                                               int nbuck, int* __restrict__ btot) {
  __shared__ int s0[512], s1[512];
  int b = blockIdx.x, t = threadIdx.x;
  int v = (t < nchunk) ? ghist[(size_t)t * nbuck + b] : 0;
  s0[t] = v;
  __syncthreads();
  int* src = s0; int* dst = s1;
  for (int off = 1; off < 512; off <<= 1) {
    int x = src[t];
    if (t >= off) x += src[t - off];
    dst[t] = x;
    __syncthreads();
    int* tmp = src; src = dst; dst = tmp;
  }
  if (t < nchunk) ghist[(size_t)t * nbuck + b] = src[t] - v;  // exclusive
  if (t == 0) btot[b] = src[511];                             // total
}

// ---------------- pass 2b: single-block exclusive scan of bucket totals ----------------
__global__ __launch_bounds__(1024) void k_bbase(const int* __restrict__ btot, int nbuck,
                                                int* __restrict__ bbase) {
  __shared__ int s0[1024], s1[1024];
  int t = threadIdx.x;
  int v = (t < nbuck) ? btot[t] : 0;
  s0[t] = v;
  __syncthreads();
  int* src = s0; int* dst = s1;
  for (int off = 1; off < 1024; off <<= 1) {
    int x = src[t];
    if (t >= off) x += src[t - off];
    dst[t] = x;
    __syncthreads();
    int* tmp = src; src = dst; dst = tmp;
  }
  if (t < nbuck) bbase[t] = src[t] - v;
}

// ---------------- pass 3: write packed records to exact slots (LDS cursors) ----------
// record: bits[16:0] = dst, bits[22:17] = src & 63
__global__ __launch_bounds__(256) void k_ebin(const int2* __restrict__ ep, int ne,
                                              int nbuck, const int* __restrict__ ghist,
                                              const int* __restrict__ bbase,
                                              unsigned* __restrict__ bins) {
  __shared__ int cur[MAXBUCK];
  int c = blockIdx.x, t = threadIdx.x;
  const int* row = ghist + (size_t)c * nbuck;
  for (int i = t; i < nbuck; i += 256) cur[i] = bbase[i] + row[i];
  __syncthreads();
  int base = c * CHUNK;
  int end = min(base + CHUNK, ne);
  for (int e = base + t; e < end; e += 256) {
    int2 p = ep[e];
    int pos = atomicAdd(&cur[p.x >> 6], 1);
    bins[pos] = (unsigned)p.y | ((unsigned)(p.x & 63) << 17);
  }
}

// ---------------- fused per-bucket: hist -> scan -> deg/isd/offsets -> CSR fill -------
__global__ __launch_bounds__(256) void k_bfinal(const int* __restrict__ bbase,
                                                const int* __restrict__ btot,
                                                const unsigned* __restrict__ bins,
                                                int n, int* __restrict__ deg,
                                                float* __restrict__ isd,
                                                int* __restrict__ offsets,
                                                int* __restrict__ csr_dst) {
  __shared__ int h[64];
  __shared__ int cur[64];
  int bk = blockIdx.x, t = threadIdx.x;
  if (t < 64) h[t] = 0;
  __syncthreads();
  int s = bbase[bk], cnt = btot[bk];
  for (int i = t; i < cnt; i += 256) atomicAdd(&h[bins[s + i] >> 17], 1);
  __syncthreads();
  if (t == 0) {
    int run = s;
    for (int j = 0; j < 64; ++j) { cur[j] = run; run += h[j]; }
  }
  __syncthreads();
  if (t < 64) {
    int node = (bk << 6) + t;
    if (node < n) {
      deg[node] = h[t];
      offsets[node] = cur[t];
      isd[node] = 1.0f / sqrtf((float)h[t]);  // deg==0 -> +inf, matches jnp.power
    }
  }
  __syncthreads();
  for (int i = t; i < cnt; i += 256) {
    unsigned r = bins[s + i];
    int pos = atomicAdd(&cur[r >> 17], 1);
    csr_dst[pos] = (int)(r & 0x1FFFFu);
  }
}

// ---------------- split-bf16 MFMA GEMM, B staged in LDS ----------------
// One 1024-thread block per 256 rows. Outputs: Tb8 = fp8(isd*t), Th = bf16(0.5*deg*t).
__global__ __launch_bounds__(1024, 4) void k_gemm(const float* __restrict__ X,
                                                  const float* __restrict__ W,
                                                  const float* __restrict__ b,
                                                  const float* __restrict__ isd,
                                                  const int* __restrict__ deg,
                                                  unsigned* __restrict__ Th,
                                                  unsigned char* __restrict__ Tb8, int M) {
  __shared__ unsigned short WhL[16384];  // fragment-major: frag*512 + lane*8 + j
  __shared__ unsigned short WlL[16384];
  int tid = threadIdx.x;

#pragma unroll
  for (int it = 0; it < 4; ++it) {
    int q = tid + it * 1024;
    int k = q >> 5;
    int c0 = (q & 31) * 4;
    float4 v = ((const float4*)W)[q];
    float vv[4] = {v.x, v.y, v.z, v.w};
#pragma unroll
    for (int j2 = 0; j2 < 4; ++j2) {
      int col = c0 + j2;
      float x = vv[j2];
      unsigned short hh = (unsigned short)(__float_as_uint(x) >> 16);
      float rem = x - __uint_as_float((unsigned)hh << 16);
      int frag = ((col >> 4) << 2) | (k >> 5);
      int ln = (((k >> 3) & 3) << 4) | (col & 15);
      int addr = frag * 512 + ln * 8 + (k & 7);
      WhL[addr] = hh;
      WlL[addr] = (unsigned short)bf16rne(rem);
    }
  }

  int wave = tid >> 6, lane = tid & 63;
  int r16 = lane & 15, kq = lane >> 4;
  int rowbase = blockIdx.x * 256 + wave * 16;
  int arow = rowbase + r16;
  bool aok = arow < M;
  const float* xr = X + ((size_t)arow << 7);

  bf16x8 ah[4], al[4];
#pragma unroll
  for (int ks = 0; ks < 4; ++ks) {
    int k0 = ks * 32 + kq * 8;
    float4 v0 = aok ? *(const float4*)(xr + k0) : make_float4(0.f, 0.f, 0.f, 0.f);
    float4 v1 = aok ? *(const float4*)(xr + k0 + 4) : make_float4(0.f, 0.f, 0.f, 0.f);
    float f[8] = {v0.x, v0.y, v0.z, v0.w, v1.x, v1.y, v1.z, v1.w};
    bf16x8 h8, l8;
#pragma unroll
    for (int j = 0; j < 8; ++j) {
      unsigned short hh = (unsigned short)(__float_as_uint(f[j]) >> 16);
      float rem = f[j] - __uint_as_float((unsigned)hh << 16);
      h8[j] = (short)hh;
      l8[j] = (short)bf16rne(rem);
    }
    ah[ks] = h8;
    al[ks] = l8;
  }
  __syncthreads();

  f32x4 acc[8] = {};
#pragma unroll
  for (int ct = 0; ct < 8; ++ct) {
#pragma unroll
    for (int ks = 0; ks < 4; ++ks) {
      int base = (ct * 4 + ks) * 512 + lane * 8;
      bf16x8 bh = *(const bf16x8*)&WhL[base];
      bf16x8 bl = *(const bf16x8*)&WlL[base];
      acc[ct] = __builtin_amdgcn_mfma_f32_16x16x32_bf16(ah[ks], bh, acc[ct], 0, 0, 0);
      acc[ct] = __builtin_amdgcn_mfma_f32_16x16x32_bf16(ah[ks], bl, acc[ct], 0, 0, 0);
      acc[ct] = __builtin_amdgcn_mfma_f32_16x16x32_bf16(al[ks], bh, acc[ct], 0, 0, 0);
    }
  }

  int orow[4];
  float isdr[4], degr[4];
#pragma unroll
  for (int r = 0; r < 4; ++r) {
    orow[r] = rowbase + kq * 4 + r;
    bool ok = orow[r] < M;
    isdr[r] = ok ? isd[orow[r]] : 0.f;
    degr[r] = ok ? 0.5f * (float)deg[orow[r]] : 0.f;
  }
#pragma unroll
  for (int ct = 0; ct < 8; ++ct) {
    int col = ct * 16 + r16;
    float bias = b[col];
#pragma unroll
    for (int r = 0; r < 4; ++r) {
      float v = acc[ct][r] + bias;
      bool ok = orow[r] < M;
      float sv = v * isdr[r];
      float so = __shfl_xor(sv, 1);
      int pk01 = __builtin_amdgcn_cvt_pk_fp8_f32(sv, so, 0, false);
      int pk23 = __shfl_xor(pk01, 2);
      if (ok && (r16 & 3) == 0) {
        unsigned dword = ((unsigned)pk01 & 0xFFFFu) | ((unsigned)pk23 << 16);
        *(unsigned*)&Tb8[((size_t)orow[r] << 7) + ct * 16 + r16] = dword;
      }
      float tv = degr[r] * v;
      float to = __shfl_xor(tv, 1);
      if (ok && !(r16 & 1)) {
        unsigned pk = bf16rne(tv) | (bf16rne(to) << 16);
        Th[((size_t)orow[r] << 6) + ct * 8 + (r16 >> 1)] = pk;
      }
    }
  }
}

// ---------------- gather: QUARTER-WAVE per node (4 nodes/wave), fp8 dwordx2 loads -----
// Lanes q*16..q*16+15 own node 4*quad+q. Lane covers 8 fp8 cols (uint2 = 8B).
// Each vmem instruction serves 4 edges (one per quarter).
__global__ __launch_bounds__(256) void k_gather(
    const unsigned* __restrict__ Th, const unsigned char* __restrict__ Tb8,
    const int* __restrict__ deg, const float* __restrict__ isd,
    const int* __restrict__ offsets, const int* __restrict__ csr_dst,
    const float* __restrict__ mm, const float* __restrict__ var,
    const float* __restrict__ gamma, const float* __restrict__ beta,
    float* __restrict__ out, int n) {
  int wave = threadIdx.x >> 6;
  int lane = threadIdx.x & 63;
  int quarter = lane >> 4;
  int l16 = lane & 15;
  int quad = blockIdx.x * 4 + wave;
  int i = 4 * quad + quarter;
  if (4 * quad >= n) return;
  bool iok = i < n;
  int degi = iok ? deg[i] : 0;
  int start = iok ? offsets[i] : 0;
  // max deg across the wave's 4 nodes
  int m1 = max(degi, __shfl_xor(degi, 16));
  int dmax = max(m1, __shfl_xor(m1, 32));
  const uint2* myrow = (const uint2*)Tb8 + l16;  // row = 16 uint2 (128B)

  f32x2 accA[8] = {}, accB[8] = {}, accC[8] = {}, accD[8] = {};
  int sl = l16 & 7;
  for (int e = 0; e < dmax; e += 8) {
    int dv = (e + sl < degi) ? csr_dst[start + e + sl] : i;  // self row when masked
    uint2 r8[8];
#pragma unroll
    for (int j = 0; j < 8; ++j) {
      int idx = __shfl(dv, (quarter << 4) + j);  // j-th index of MY node
      r8[j] = myrow[(unsigned)idx << 4];
    }
#pragma unroll
    for (int j = 0; j < 8; ++j) {
      bool live = (e + j < degi);
      int r0 = live ? (int)r8[j].x : 0;
      int r1 = live ? (int)r8[j].y : 0;
      accA[j] += __builtin_amdgcn_cvt_pk_f32_fp8(r0, false);
      accB[j] += __builtin_amdgcn_cvt_pk_f32_fp8(r0, true);
      accC[j] += __builtin_amdgcn_cvt_pk_f32_fp8(r1, false);
      accD[j] += __builtin_amdgcn_cvt_pk_f32_fp8(r1, true);
    }
  }
  f32x2 sA = ((accA[0] + accA[1]) + (accA[2] + accA[3])) +
             ((accA[4] + accA[5]) + (accA[6] + accA[7]));
  f32x2 sB = ((accB[0] + accB[1]) + (accB[2] + accB[3])) +
             ((accB[4] + accB[5]) + (accB[6] + accB[7]));
  f32x2 sC = ((accC[0] + accC[1]) + (accC[2] + accC[3])) +
             ((accC[4] + accC[5]) + (accC[6] + accC[7]));
  f32x2 sD = ((accD[0] + accD[1]) + (accD[2] + accD[3])) +
             ((accD[4] + accD[5]) + (accD[6] + accD[7]));

  if (!iok) return;
  // agg for cols 8*l16 .. 8*l16+7
  float agg[8] = {};
  if (degi > 0) {
    uint4 th = *(const uint4*)(Th + ((size_t)i << 6) + l16 * 4);  // 8 bf16 self terms
    float hsi = 0.5f * isd[i];
    agg[0] = hsi * sA.x + bflo(th.x);
    agg[1] = hsi * sA.y + bfhi(th.x);
    agg[2] = hsi * sB.x + bflo(th.y);
    agg[3] = hsi * sB.y + bfhi(th.y);
    agg[4] = hsi * sC.x + bflo(th.z);
    agg[5] = hsi * sC.y + bfhi(th.z);
    agg[6] = hsi * sD.x + bflo(th.w);
    agg[7] = hsi * sD.y + bfhi(th.w);
  }
  float res[8];
#pragma unroll
  for (int h = 0; h < 2; ++h) {
    float4 mmv = ((const float4*)mm)[l16 * 2 + h];
    float4 vv = ((const float4*)var)[l16 * 2 + h];
    float4 gv = ((const float4*)gamma)[l16 * 2 + h];
    float4 bv = ((const float4*)beta)[l16 * 2 + h];
    res[4 * h + 0] = (agg[4 * h + 0] - mmv.x) * rsqrtf(vv.x + BN_EPS) * gv.x + bv.x;
    res[4 * h + 1] = (agg[4 * h + 1] - mmv.y) * rsqrtf(vv.y + BN_EPS) * gv.y + bv.y;
    res[4 * h + 2] = (agg[4 * h + 2] - mmv.z) * rsqrtf(vv.z + BN_EPS) * gv.z + bv.z;
    res[4 * h + 3] = (agg[4 * h + 3] - mmv.w) * rsqrtf(vv.w + BN_EPS) * gv.w + bv.w;
  }
  float* op = out + ((size_t)i << 7) + l16 * 8;
  *(float4*)op = make_float4(res[0], res[1], res[2], res[3]);
  *(float4*)(op + 4) = make_float4(res[4], res[5], res[6], res[7]);
}

static inline size_t align_up(size_t x) { return (x + 255) & ~(size_t)255; }

extern "C" void kernel_launch(void* const* d_in, const int* in_sizes, int n_in,
                              void* d_out, int out_size, void* d_ws, size_t ws_size,
                              hipStream_t stream) {
  const int2* ep = (const int2*)d_in[0];
  const float* X = (const float*)d_in[1];
  const float* W = (const float*)d_in[2];
  const float* b = (const float*)d_in[3];
  const float* gamma = (const float*)d_in[4];
  const float* beta = (const float*)d_in[5];
  const float* mm = (const float*)d_in[6];
  const float* var = (const float*)d_in[7];
  float* out = (float*)d_out;

  const int ne = in_sizes[0] / 2;
  const int n = in_sizes[1] / 128;
  const int nbuck = (n + 63) >> 6;              // <= MAXBUCK
  const int nchunk = (ne + CHUNK - 1) / CHUNK;  // <= 512

  char* p = (char*)d_ws;
  int* deg = (int*)p;        p += align_up((size_t)n * 4);
  float* isd = (float*)p;    p += align_up((size_t)n * 4);
  int* offsets = (int*)p;    p += align_up((size_t)n * 4);
  int* btot = (int*)p;       p += align_up((size_t)nbuck * 4);
  int* bbase = (int*)p;      p += align_up((size_t)nbuck * 4);
  int* ghist = (int*)p;      p += align_up((size_t)nchunk * nbuck * 4);
  int* csr_dst = (int*)p;    p += align_up((size_t)ne * 4);
  unsigned* bins = (unsigned*)p; p += align_up((size_t)ne * 4);
  unsigned* Th = (unsigned*)p;   p += align_up((size_t)n * 64 * 4);
  unsigned char* Tb8 = (unsigned char*)p; p += align_up((size_t)n * 128);

  k_ehist<<<nchunk, 256, 0, stream>>>(ep, ne, nbuck, ghist);
  k_bscan<<<nbuck, 512, 0, stream>>>(ghist, nchunk, nbuck, btot);
  k_bbase<<<1, 1024, 0, stream>>>(btot, nbuck, bbase);
  k_ebin<<<nchunk, 256, 0, stream>>>(ep, ne, nbuck, ghist, bbase, bins);
  k_bfinal<<<nbuck, 256, 0, stream>>>(bbase, btot, bins, n, deg, isd, offsets, csr_dst);
  k_gemm<<<(n + 255) / 256, 1024, 0, stream>>>(X, W, b, isd, deg, Th, Tb8, n);
  int quads = (n + 3) / 4;
  k_gather<<<(quads + 3) / 4, 256, 0, stream>>>(Th, Tb8, deg, isd, offsets, csr_dst,
                                                mm, var, gamma, beta, out, n);
}

// Round 16
// 80.787 us; speedup vs baseline: 5.7364x; 1.0709x over previous
//
#include <hip/hip_runtime.h>
#include <math.h>

#define BN_EPS 0.001f
#define CHUNK 2048          // edges per chunk; nchunk = ceil(ne/CHUNK) must be <= 512
#define MAXBUCK 1024        // nbuck = ceil(n/64) must be <= 1024

typedef __attribute__((ext_vector_type(8))) short bf16x8;
typedef __attribute__((ext_vector_type(4))) float f32x4;
typedef __attribute__((ext_vector_type(2))) float f32x2;

__device__ inline unsigned bf16rne(float f) {
  unsigned u = __float_as_uint(f);
  return (u + 0x7fffu + ((u >> 16) & 1u)) >> 16;
}
__device__ inline float bflo(unsigned r) { return __uint_as_float(r << 16); }
__device__ inline float bfhi(unsigned r) { return __uint_as_float(r & 0xffff0000u); }

// ---------------- pass 1: per-chunk LDS histogram by bucket (src>>6) ----------------
__global__ __launch_bounds__(256) void k_ehist(const int2* __restrict__ ep, int ne,
                                               int nbuck, int* __restrict__ ghist) {
  __shared__ int h[MAXBUCK];
  int c = blockIdx.x, t = threadIdx.x;
  for (int i = t; i < nbuck; i += 256) h[i] = 0;
  __syncthreads();
  int base = c * CHUNK;
  int end = min(base + CHUNK, ne);
  for (int e = base + t; e < end; e += 256) atomicAdd(&h[ep[e].x >> 6], 1);
  __syncthreads();
  int* row = ghist + (size_t)c * nbuck;
  for (int i = t; i < nbuck; i += 256) row[i] = h[i];
}

// ---------------- pass 2a: per-bucket exclusive scan over chunks (in place) + totals ----
__global__ __launch_bounds__(512) void k_bscan(int* __restrict__ ghist, int nchunk,
                                               int nbuck, int* __restrict__ btot) {
  __shared__ int s0[512], s1[512];
  int b = blockIdx.x, t = threadIdx.x;
  int v = (t < nchunk) ? ghist[(size_t)t * nbuck + b] : 0;
  s0[t] = v;
  __syncthreads();
  int* src = s0; int* dst = s1;
  for (int off = 1; off < 512; off <<= 1) {
    int x = src[t];
    if (t >= off) x += src[t - off];
    dst[t] = x;
    __syncthreads();
    int* tmp = src; src = dst; dst = tmp;
  }
  if (t < nchunk) ghist[(size_t)t * nbuck + b] = src[t] - v;  // exclusive
  if (t == 0) btot[b] = src[511];                             // total
}

// ---------------- pass 2b: single-block exclusive scan of bucket totals ----------------
__global__ __launch_bounds__(1024) void k_bbase(const int* __restrict__ btot, int nbuck,
                                                int* __restrict__ bbase) {
  __shared__ int s0[1024], s1[1024];
  int t = threadIdx.x;
  int v = (t < nbuck) ? btot[t] : 0;
  s0[t] = v;
  __syncthreads();
  int* src = s0; int* dst = s1;
  for (int off = 1; off < 1024; off <<= 1) {
    int x = src[t];
    if (t >= off) x += src[t - off];
    dst[t] = x;
    __syncthreads();
    int* tmp = src; src = dst; dst = tmp;
  }
  if (t < nbuck) bbase[t] = src[t] - v;
}

// ---------------- pass 3: write packed records to exact slots (LDS cursors) ----------
// record: bits[16:0] = dst, bits[22:17] = src & 63
__global__ __launch_bounds__(256) void k_ebin(const int2* __restrict__ ep, int ne,
                                              int nbuck, const int* __restrict__ ghist,
                                              const int* __restrict__ bbase,
                                              unsigned* __restrict__ bins) {
  __shared__ int cur[MAXBUCK];
  int c = blockIdx.x, t = threadIdx.x;
  const int* row = ghist + (size_t)c * nbuck;
  for (int i = t; i < nbuck; i += 256) cur[i] = bbase[i] + row[i];
  __syncthreads();
  int base = c * CHUNK;
  int end = min(base + CHUNK, ne);
  for (int e = base + t; e < end; e += 256) {
    int2 p = ep[e];
    int pos = atomicAdd(&cur[p.x >> 6], 1);
    bins[pos] = (unsigned)p.y | ((unsigned)(p.x & 63) << 17);
  }
}

// ---------------- fused per-bucket: hist -> scan -> deg/isd/offsets -> CSR fill -------
__global__ __launch_bounds__(256) void k_bfinal(const int* __restrict__ bbase,
                                                const int* __restrict__ btot,
                                                const unsigned* __restrict__ bins,
                                                int n, int* __restrict__ deg,
                                                float* __restrict__ isd,
                                                int* __restrict__ offsets,
                                                int* __restrict__ csr_dst) {
  __shared__ int h[64];
  __shared__ int cur[64];
  int bk = blockIdx.x, t = threadIdx.x;
  if (t < 64) h[t] = 0;
  __syncthreads();
  int s = bbase[bk], cnt = btot[bk];
  for (int i = t; i < cnt; i += 256) atomicAdd(&h[bins[s + i] >> 17], 1);
  __syncthreads();
  if (t == 0) {
    int run = s;
    for (int j = 0; j < 64; ++j) { cur[j] = run; run += h[j]; }
  }
  __syncthreads();
  if (t < 64) {
    int node = (bk << 6) + t;
    if (node < n) {
      deg[node] = h[t];
      offsets[node] = cur[t];
      isd[node] = 1.0f / sqrtf((float)h[t]);  // deg==0 -> +inf, matches jnp.power
    }
  }
  __syncthreads();
  for (int i = t; i < cnt; i += 256) {
    unsigned r = bins[s + i];
    int pos = atomicAdd(&cur[r >> 17], 1);
    csr_dst[pos] = (int)(r & 0x1FFFFu);
  }
}

// ---------------- split-bf16 MFMA GEMM, B staged in LDS ----------------
// One 1024-thread block per 256 rows. Outputs: Tb8 = fp8(isd*t), Th = bf16(0.5*deg*t).
__global__ __launch_bounds__(1024, 4) void k_gemm(const float* __restrict__ X,
                                                  const float* __restrict__ W,
                                                  const float* __restrict__ b,
                                                  const float* __restrict__ isd,
                                                  const int* __restrict__ deg,
                                                  unsigned* __restrict__ Th,
                                                  unsigned char* __restrict__ Tb8, int M) {
  __shared__ unsigned short WhL[16384];  // fragment-major: frag*512 + lane*8 + j
  __shared__ unsigned short WlL[16384];
  int tid = threadIdx.x;

#pragma unroll
  for (int it = 0; it < 4; ++it) {
    int q = tid + it * 1024;
    int k = q >> 5;
    int c0 = (q & 31) * 4;
    float4 v = ((const float4*)W)[q];
    float vv[4] = {v.x, v.y, v.z, v.w};
#pragma unroll
    for (int j2 = 0; j2 < 4; ++j2) {
      int col = c0 + j2;
      float x = vv[j2];
      unsigned short hh = (unsigned short)(__float_as_uint(x) >> 16);
      float rem = x - __uint_as_float((unsigned)hh << 16);
      int frag = ((col >> 4) << 2) | (k >> 5);
      int ln = (((k >> 3) & 3) << 4) | (col & 15);
      int addr = frag * 512 + ln * 8 + (k & 7);
      WhL[addr] = hh;
      WlL[addr] = (unsigned short)bf16rne(rem);
    }
  }

  int wave = tid >> 6, lane = tid & 63;
  int r16 = lane & 15, kq = lane >> 4;
  int rowbase = blockIdx.x * 256 + wave * 16;
  int arow = rowbase + r16;
  bool aok = arow < M;
  const float* xr = X + ((size_t)arow << 7);

  bf16x8 ah[4], al[4];
#pragma unroll
  for (int ks = 0; ks < 4; ++ks) {
    int k0 = ks * 32 + kq * 8;
    float4 v0 = aok ? *(const float4*)(xr + k0) : make_float4(0.f, 0.f, 0.f, 0.f);
    float4 v1 = aok ? *(const float4*)(xr + k0 + 4) : make_float4(0.f, 0.f, 0.f, 0.f);
    float f[8] = {v0.x, v0.y, v0.z, v0.w, v1.x, v1.y, v1.z, v1.w};
    bf16x8 h8, l8;
#pragma unroll
    for (int j = 0; j < 8; ++j) {
      unsigned short hh = (unsigned short)(__float_as_uint(f[j]) >> 16);
      float rem = f[j] - __uint_as_float((unsigned)hh << 16);
      h8[j] = (short)hh;
      l8[j] = (short)bf16rne(rem);
    }
    ah[ks] = h8;
    al[ks] = l8;
  }
  __syncthreads();

  f32x4 acc[8] = {};
#pragma unroll
  for (int ct = 0; ct < 8; ++ct) {
#pragma unroll
    for (int ks = 0; ks < 4; ++ks) {
      int base = (ct * 4 + ks) * 512 + lane * 8;
      bf16x8 bh = *(const bf16x8*)&WhL[base];
      bf16x8 bl = *(const bf16x8*)&WlL[base];
      acc[ct] = __builtin_amdgcn_mfma_f32_16x16x32_bf16(ah[ks], bh, acc[ct], 0, 0, 0);
      acc[ct] = __builtin_amdgcn_mfma_f32_16x16x32_bf16(ah[ks], bl, acc[ct], 0, 0, 0);
      acc[ct] = __builtin_amdgcn_mfma_f32_16x16x32_bf16(al[ks], bh, acc[ct], 0, 0, 0);
    }
  }

  int orow[4];
  float isdr[4], degr[4];
#pragma unroll
  for (int r = 0; r < 4; ++r) {
    orow[r] = rowbase + kq * 4 + r;
    bool ok = orow[r] < M;
    isdr[r] = ok ? isd[orow[r]] : 0.f;
    degr[r] = ok ? 0.5f * (float)deg[orow[r]] : 0.f;
  }
#pragma unroll
  for (int ct = 0; ct < 8; ++ct) {
    int col = ct * 16 + r16;
    float bias = b[col];
#pragma unroll
    for (int r = 0; r < 4; ++r) {
      float v = acc[ct][r] + bias;
      bool ok = orow[r] < M;
      float sv = v * isdr[r];
      float so = __shfl_xor(sv, 1);
      int pk01 = __builtin_amdgcn_cvt_pk_fp8_f32(sv, so, 0, false);
      int pk23 = __shfl_xor(pk01, 2);
      if (ok && (r16 & 3) == 0) {
        unsigned dword = ((unsigned)pk01 & 0xFFFFu) | ((unsigned)pk23 << 16);
        *(unsigned*)&Tb8[((size_t)orow[r] << 7) + ct * 16 + r16] = dword;
      }
      float tv = degr[r] * v;
      float to = __shfl_xor(tv, 1);
      if (ok && !(r16 & 1)) {
        unsigned pk = bf16rne(tv) | (bf16rne(to) << 16);
        Th[((size_t)orow[r] << 6) + ct * 8 + (r16 >> 1)] = pk;
      }
    }
  }
}

// ---------------- gather: HALF-WAVE per node (2 nodes/wave), fp8 dword loads ----------
// Lanes 0-31 own node 2p, lanes 32-63 own node 2p+1. Lane covers 4 fp8 cols (dword).
// csr_dst index loads are software-pipelined one batch ahead.
__global__ __launch_bounds__(256) void k_gather(
    const unsigned* __restrict__ Th, const unsigned char* __restrict__ Tb8,
    const int* __restrict__ deg, const float* __restrict__ isd,
    const int* __restrict__ offsets, const int* __restrict__ csr_dst,
    const float* __restrict__ mm, const float* __restrict__ var,
    const float* __restrict__ gamma, const float* __restrict__ beta,
    float* __restrict__ out, int n) {
  int wave = threadIdx.x >> 6;
  int lane = threadIdx.x & 63;
  int half = lane >> 5;
  int l32 = lane & 31;
  int pair = blockIdx.x * 4 + wave;
  int i = 2 * pair + half;
  if (2 * pair >= n) return;
  bool iok = i < n;
  int degi = iok ? deg[i] : 0;
  int start = iok ? offsets[i] : 0;
  int dother = __shfl(degi, lane ^ 32);
  int dmax = max(degi, dother);
  const unsigned* myrows = (const unsigned*)Tb8 + l32;

  f32x2 accA[8] = {}, accB[8] = {};
  int sl = l32 & 7;
  int dv = (sl < degi) ? csr_dst[start + sl] : i;  // prefetched batch 0
  for (int e = 0; e < dmax; e += 8) {
    int dv_next = (e + 8 + sl < degi) ? csr_dst[start + e + 8 + sl] : i;  // prefetch
    unsigned r8[8];
#pragma unroll
    for (int j = 0; j < 8; ++j) {
      int idx = __shfl(dv, (half << 5) + j);
      r8[j] = myrows[(unsigned)idx << 5];
    }
#pragma unroll
    for (int j = 0; j < 8; ++j) {
      int rr = (e + j < degi) ? (int)r8[j] : 0;
      accA[j] += __builtin_amdgcn_cvt_pk_f32_fp8(rr, false);
      accB[j] += __builtin_amdgcn_cvt_pk_f32_fp8(rr, true);
    }
    dv = dv_next;
  }
  f32x2 sA = ((accA[0] + accA[1]) + (accA[2] + accA[3])) +
             ((accA[4] + accA[5]) + (accA[6] + accA[7]));
  f32x2 sB = ((accB[0] + accB[1]) + (accB[2] + accB[3])) +
             ((accB[4] + accB[5]) + (accB[6] + accB[7]));

  if (!iok) return;
  float4 aggv = make_float4(0.f, 0.f, 0.f, 0.f);
  if (degi > 0) {
    uint2 th = ((const uint2*)(Th + ((size_t)i << 6)))[l32];
    float hsi = 0.5f * isd[i];
    aggv.x = hsi * sA.x + bflo(th.x);
    aggv.y = hsi * sA.y + bfhi(th.x);
    aggv.z = hsi * sB.x + bflo(th.y);
    aggv.w = hsi * sB.y + bfhi(th.y);
  }
  float4 mmv = ((const float4*)mm)[l32];
  float4 vv = ((const float4*)var)[l32];
  float4 gv = ((const float4*)gamma)[l32];
  float4 bv = ((const float4*)beta)[l32];
  float4 res;
  res.x = (aggv.x - mmv.x) * rsqrtf(vv.x + BN_EPS) * gv.x + bv.x;
  res.y = (aggv.y - mmv.y) * rsqrtf(vv.y + BN_EPS) * gv.y + bv.y;
  res.z = (aggv.z - mmv.z) * rsqrtf(vv.z + BN_EPS) * gv.z + bv.z;
  res.w = (aggv.w - mmv.w) * rsqrtf(vv.w + BN_EPS) * gv.w + bv.w;
  ((float4*)(out + ((size_t)i << 7)))[l32] = res;
}

static inline size_t align_up(size_t x) { return (x + 255) & ~(size_t)255; }

extern "C" void kernel_launch(void* const* d_in, const int* in_sizes, int n_in,
                              void* d_out, int out_size, void* d_ws, size_t ws_size,
                              hipStream_t stream) {
  const int2* ep = (const int2*)d_in[0];
  const float* X = (const float*)d_in[1];
  const float* W = (const float*)d_in[2];
  const float* b = (const float*)d_in[3];
  const float* gamma = (const float*)d_in[4];
  const float* beta = (const float*)d_in[5];
  const float* mm = (const float*)d_in[6];
  const float* var = (const float*)d_in[7];
  float* out = (float*)d_out;

  const int ne = in_sizes[0] / 2;
  const int n = in_sizes[1] / 128;
  const int nbuck = (n + 63) >> 6;              // <= MAXBUCK
  const int nchunk = (ne + CHUNK - 1) / CHUNK;  // <= 512

  char* p = (char*)d_ws;
  int* deg = (int*)p;        p += align_up((size_t)n * 4);
  float* isd = (float*)p;    p += align_up((size_t)n * 4);
  int* offsets = (int*)p;    p += align_up((size_t)n * 4);
  int* btot = (int*)p;       p += align_up((size_t)nbuck * 4);
  int* bbase = (int*)p;      p += align_up((size_t)nbuck * 4);
  int* ghist = (int*)p;      p += align_up((size_t)nchunk * nbuck * 4);
  int* csr_dst = (int*)p;    p += align_up((size_t)ne * 4);
  unsigned* bins = (unsigned*)p; p += align_up((size_t)ne * 4);
  unsigned* Th = (unsigned*)p;   p += align_up((size_t)n * 64 * 4);
  unsigned char* Tb8 = (unsigned char*)p; p += align_up((size_t)n * 128);

  k_ehist<<<nchunk, 256, 0, stream>>>(ep, ne, nbuck, ghist);
  k_bscan<<<nbuck, 512, 0, stream>>>(ghist, nchunk, nbuck, btot);
  k_bbase<<<1, 1024, 0, stream>>>(btot, nbuck, bbase);
  k_ebin<<<nchunk, 256, 0, stream>>>(ep, ne, nbuck, ghist, bbase, bins);
  k_bfinal<<<nbuck, 256, 0, stream>>>(bbase, btot, bins, n, deg, isd, offsets, csr_dst);
  k_gemm<<<(n + 255) / 256, 1024, 0, stream>>>(X, W, b, isd, deg, Th, Tb8, n);
  int pairs = (n + 1) / 2;
  k_gather<<<(pairs + 3) / 4, 256, 0, stream>>>(Th, Tb8, deg, isd, offsets, csr_dst,
                                                mm, var, gamma, beta, out, n);
}